// Round 2
// baseline (111.112 us; speedup 1.0000x reference)
//
#include <hip/hip_runtime.h>
#include <hip/hip_bf16.h>
#include <math.h>

#define B 16
#define C 512
#define CQ 256
#define N 1024

typedef short bf16x8 __attribute__((ext_vector_type(8)));
typedef _Float16 f16x8 __attribute__((ext_vector_type(8)));
typedef float f32x4 __attribute__((ext_vector_type(4)));
typedef unsigned short ushort;

__device__ __forceinline__ unsigned short f2bf(float f) {
    __hip_bfloat16 h = __float2bfloat16(f);
    return *(unsigned short*)&h;
}
__device__ __forceinline__ ushort f2h(float f) {
    _Float16 h = (_Float16)f;
    return *(ushort*)&h;
}
__device__ __forceinline__ float h2f(ushort u) {
    _Float16 h = *(_Float16*)&u;
    return (float)h;
}
__device__ __forceinline__ f16x8 as_h(bf16x8 v) {
    union { bf16x8 s; f16x8 h; } u; u.s = v; return u.h;
}

__device__ __forceinline__ void gload16(void* lds, const void* g) {
    __builtin_amdgcn_global_load_lds(
        (const __attribute__((address_space(1))) void*)g,
        (__attribute__((address_space(3))) void*)lds, 16, 0, 0);
}

__device__ __forceinline__ void barrier_lgkm() {
    asm volatile("s_waitcnt lgkmcnt(0)" ::: "memory");
    __builtin_amdgcn_s_barrier();
    __builtin_amdgcn_sched_barrier(0);
}

// ---------------------------------------------------------------------------
// MFMA GEMM, BK=128, XOR-swizzled LDS. C[b][row][col] = sum_k A[b][row][k] *
// BT[b][col][k] (+bias). 128x128 tile, 256 thr = 4 waves (2x2). K % 128 == 0.
// OUT_MODE: 0 fp32, 1 bf16, 3 fp16. BIAS_MODE: 0 none, 1 row, 2 col.
// XSWZ: XCD remap (grid x*y==32, z==16). DT: 0 bf16 MFMA, 1 fp16 MFMA.
// ---------------------------------------------------------------------------
template<int OUT_MODE, int BIAS_MODE, int XSWZ, int DT>
__global__ __launch_bounds__(256) void gemm128s(
    const ushort* __restrict__ A, long long sA,
    const ushort* __restrict__ BT, long long sB,
    void* __restrict__ Ch, long long sC,
    const float* __restrict__ bias, int K, int Ncols)
{
    __shared__ __align__(16) ushort As[128 * 128];   // 32 KB
    __shared__ __align__(16) ushort Bs[128 * 128];   // 32 KB

    int bx, by, bz;
    if constexpr (XSWZ) {
        const int lin  = blockIdx.x + gridDim.x * (blockIdx.y + gridDim.y * blockIdx.z);
        const int xcd  = lin & 7;
        const int slot = lin >> 3;          // 0..63
        bz = xcd + 8 * (slot >> 5);         // batch
        const int wxy = slot & 31;
        bx = wxy % gridDim.x;
        by = wxy / gridDim.x;
    } else {
        bx = blockIdx.x; by = blockIdx.y; bz = blockIdx.z;
    }

    const int tid  = threadIdx.x;
    const int lane = tid & 63;
    const int w    = tid >> 6;
    const int wr   = (w >> 1) * 64;
    const int wc   = (w & 1) * 64;
    const int fr   = lane & 15;
    const int ko2  = (lane >> 4) * 16;      // byte offset of lane's K-octet

    const int brow = by * 128;
    const int bcol = bx * 128;
    const size_t K2 = (size_t)K * 2;

    const char* Ab = (const char*)(A  + (size_t)bz * sA + (size_t)brow * K);
    const char* Bb = (const char*)(BT + (size_t)bz * sB + (size_t)bcol * K);

    const int sr = tid >> 4;            // staging row base 0..15
    const int ss = (tid & 15) * 16;     // byte seg within 256B row

    f32x4 acc[4][4] = {};

    for (int k0 = 0; k0 < K; k0 += 128) {
#pragma unroll
        for (int p = 0; p < 8; ++p) {
            const int row = p * 16 + sr;
            const size_t so = (size_t)row * K2 + (size_t)k0 * 2
                            + (size_t)(ss ^ ((row & 15) << 4));
            gload16((char*)As + p * 4096 + tid * 16, Ab + so);
            gload16((char*)Bs + p * 4096 + tid * 16, Bb + so);
        }
        __syncthreads();
#pragma unroll
        for (int k32 = 0; k32 < 4; ++k32) {
            const int kswz = (k32 * 64 + ko2) ^ (fr << 4);
            bf16x8 ah[4], bh[4];
#pragma unroll
            for (int m = 0; m < 4; ++m)
                ah[m] = *(const bf16x8*)((const char*)As + (wr + m * 16 + fr) * 256 + kswz);
#pragma unroll
            for (int n = 0; n < 4; ++n)
                bh[n] = *(const bf16x8*)((const char*)Bs + (wc + n * 16 + fr) * 256 + kswz);
            if constexpr (DT == 1) {
#pragma unroll
                for (int m = 0; m < 4; ++m)
#pragma unroll
                    for (int n = 0; n < 4; ++n)
                        acc[m][n] = __builtin_amdgcn_mfma_f32_16x16x32_f16(
                            as_h(ah[m]), as_h(bh[n]), acc[m][n], 0, 0, 0);
            } else {
#pragma unroll
                for (int m = 0; m < 4; ++m)
#pragma unroll
                    for (int n = 0; n < 4; ++n)
                        acc[m][n] = __builtin_amdgcn_mfma_f32_16x16x32_bf16(
                            ah[m], bh[n], acc[m][n], 0, 0, 0);
            }
        }
        __syncthreads();
    }

    // Epilogue: C/D layout col = lane&15, row = (lane>>4)*4 + r
    const int crow = brow + wr + (lane >> 4) * 4;
    const int ccol = bcol + wc + fr;
    const size_t cbase = (size_t)bz * sC;
#pragma unroll
    for (int m = 0; m < 4; ++m) {
#pragma unroll
        for (int n = 0; n < 4; ++n) {
            float cb = (BIAS_MODE == 2) ? bias[ccol + n * 16] : 0.f;
#pragma unroll
            for (int r = 0; r < 4; ++r) {
                int row = crow + m * 16 + r;
                int col = ccol + n * 16;
                float vv = acc[m][n][r];
                if (BIAS_MODE == 1) vv += bias[row];
                if (BIAS_MODE == 2) vv += cb;
                size_t idx = cbase + (size_t)row * Ncols + col;
                if (OUT_MODE == 0)      ((float*)Ch)[idx]  = vv;
                else if (OUT_MODE == 1) ((ushort*)Ch)[idx] = f2bf(vv);
                else                    ((ushort*)Ch)[idx] = f2h(vv);
            }
        }
    }
}

// ---------------------------------------------------------------------------
// Fully fused attention, 1024 threads = 16 waves/CU (4 waves/SIMD; LDS pins
// us to 1 wg/CU).
// __launch_bounds__(1024, 4): min 4 waves/EU => register cap 512/4 = 128
// unified regs/wave. Round-1's default heuristic picked 64 VGPRs (targeting
// an 8-wave/SIMD occupancy that LDS makes impossible) and spilled ~55 MB of
// scratch per dispatch (FETCH +19 MB, WRITE +36 MB). Demand by phase:
//   QK  ~112 (acc 64 AGPR + a_h 32 + addr)
//   pack~108 (acc 64 + hp 32)
//   PV  ~100 (hp 32 + apv 32 + frags 24)
// all under 128 => spill-free at this cap.
// QK: 16 waves = 2 row-groups x 8 col-waves; acc[8][2]; b_h reused over m.
//     4-buffer depth-2 counted-vmcnt schedule (2 loads/thread => vmcnt 4/2/0).
// PV: 16 waves x 32 channels; V double-buffer + full-drain schedule.
// Epilogue: pad-33 fp32 repack + dual store.
// ---------------------------------------------------------------------------
__global__ __launch_bounds__(1024, 4) void fused_attn(
    const ushort* __restrict__ qk, const ushort* __restrict__ vmat,
    const float* __restrict__ Wa, const float* __restrict__ ba,
    const float* __restrict__ gamma, const float* __restrict__ x,
    float* __restrict__ dout)
{
    __shared__ __align__(16) char lds[149504];
    __shared__ float redbuf[2][2][8][32];
    __shared__ float redA[16][64];
    __shared__ float agL[64];

    const int tid  = threadIdx.x;
    const int lane = tid & 63;
    const int w    = tid >> 6;           // 0..15
    const int g    = w >> 3;             // QK row group 0/1 (32 rows each)
    const int wg8  = w & 7;              // QK col-wave within group
    const int fr   = lane & 15;
    const int il0  = (lane >> 4) * 4;
    const int ko2  = (lane >> 4) * 16;   // byte offset of lane's K-octet

    // XCD-aware bijective remap (256 wgs, 8 XCDs => 2 batches/XCD)
    const int wgid = blockIdx.x + gridDim.x * blockIdx.y;
    const int nid  = (wgid & 7) * 32 + (wgid >> 3);
    const int b    = nid >> 4;
    const int i0   = (nid & 15) * 64;

    const char* qkB = (const char*)qk + (size_t)b * N * 1024;
    const char* vB  = (const char*)vmat + (size_t)b * C * N * 2;

    const int srow = tid >> 4;          // 0..63
    const int ssg  = (tid & 15) * 16;   // byte seg in 256B row

    // ---- q fragments for K-half 0 only (reloaded for half 1 at s==8) ----
    f16x8 a_h[2][4];
#pragma unroll
    for (int m = 0; m < 2; ++m) {
        const char* qr = qkB + (size_t)(i0 + g * 32 + m * 16 + fr) * 1024
                       + (lane >> 4) * 16;
#pragma unroll
        for (int k32 = 0; k32 < 4; ++k32)
            a_h[m][k32] = *(const f16x8*)(qr + k32 * 64);
    }

    // ---- QK staging: 4 buffers of 32 KB, 2 loads/thread/stage ----
    auto stageK = [&](int s) {
        const int jt_  = s & 7;
        const int ks0_ = s >> 3;
        char* dst = lds + (s & 3) * 32768;
#pragma unroll
        for (int p = 0; p < 2; ++p) {
            const int row = p * 64 + srow;
            const size_t so = (size_t)(jt_ * 128 + row) * 1024 + 512
                            + (size_t)(ks0_ * 256)
                            + (size_t)(ssg ^ ((row & 15) << 4));
            gload16(dst + p * 16384 + tid * 16, qkB + so);
        }
    };

    f32x4 acc[8][2];
#pragma unroll
    for (int sl = 0; sl < 8; ++sl)
#pragma unroll
        for (int m = 0; m < 2; ++m)
            acc[sl][m] = (f32x4){0.f, 0.f, 0.f, 0.f};

    stageK(0);
    stageK(1);

#pragma unroll
    for (int s = 0; s < 16; ++s) {
        if (s == 8) {   // reload q frags for K-half 1 (L2-hot, 8 loads)
#pragma unroll
            for (int m = 0; m < 2; ++m) {
                const char* qr = qkB + (size_t)(i0 + g * 32 + m * 16 + fr) * 1024
                               + 256 + (lane >> 4) * 16;
#pragma unroll
                for (int k32 = 0; k32 < 4; ++k32)
                    a_h[m][k32] = *(const f16x8*)(qr + k32 * 64);
            }
        }
        if (s + 2 < 16) stageK(s + 2);
        if (s < 14)       asm volatile("s_waitcnt vmcnt(4)" ::: "memory");
        else if (s == 14) asm volatile("s_waitcnt vmcnt(2)" ::: "memory");
        else              asm volatile("s_waitcnt vmcnt(0)" ::: "memory");
        __builtin_amdgcn_s_barrier();
        __builtin_amdgcn_sched_barrier(0);
        const char* kb = lds + (s & 3) * 32768;
        const int sl   = s & 7;
        const int jrow = wg8 * 16 + fr;      // 0..127 within slab
        const int rb   = jrow * 256;
#pragma unroll
        for (int k32 = 0; k32 < 4; ++k32) {
            const int kswz = (k32 * 64 + ko2) ^ (fr << 4);
            f16x8 b_h = *(const f16x8*)(kb + rb + kswz);
#pragma unroll
            for (int m = 0; m < 2; ++m)
                acc[sl][m] = __builtin_amdgcn_mfma_f32_16x16x32_f16(
                    a_h[m][k32], b_h, acc[sl][m], 0, 0, 0);
        }
    }

    // ---- V staging (2 x 64 KB), 4 loads/thread ----
    auto stageV = [&](int j) {
        char* dst = lds + (j & 1) * 65536;
#pragma unroll
        for (int p = 0; p < 4; ++p) {
            const int ch = p * 1024 + tid;
            const int row = ch >> 3;
            const int sg  = (ch & 7) * 16;
            const size_t so = (size_t)row * (N * 2) + (size_t)(j * 128)
                            + (size_t)(sg ^ ((row & 7) << 4));
            gload16(dst + ch * 16, vB + so);
        }
    };
    stageV(0);                           // in flight under softmax

    // ---- row max (lgkm-only barriers; vmcnt untouched) ----
    float mx[2][4];
#pragma unroll
    for (int m = 0; m < 2; ++m)
#pragma unroll
        for (int r = 0; r < 4; ++r) {
            float v = acc[0][m][r];
#pragma unroll
            for (int sl = 1; sl < 8; ++sl) v = fmaxf(v, acc[sl][m][r]);
            mx[m][r] = v;
        }
#pragma unroll
    for (int off = 1; off < 16; off <<= 1)
#pragma unroll
        for (int m = 0; m < 2; ++m)
#pragma unroll
            for (int r = 0; r < 4; ++r)
                mx[m][r] = fmaxf(mx[m][r], __shfl_xor(mx[m][r], off, 64));
    if (fr == 0) {
#pragma unroll
        for (int m = 0; m < 2; ++m)
#pragma unroll
            for (int r = 0; r < 4; ++r)
                redbuf[0][g][wg8][m * 16 + il0 + r] = mx[m][r];
    }
    barrier_lgkm();
#pragma unroll
    for (int m = 0; m < 2; ++m)
#pragma unroll
        for (int r = 0; r < 4; ++r) {
            const int row = m * 16 + il0 + r;
            float v = redbuf[0][g][0][row];
#pragma unroll
            for (int q = 1; q < 8; ++q) v = fmaxf(v, redbuf[0][g][q][row]);
            mx[m][r] = v;
        }

    // ---- exp + row sum ----
    float sm[2][4] = {};
#pragma unroll
    for (int sl = 0; sl < 8; ++sl)
#pragma unroll
        for (int m = 0; m < 2; ++m) {
            f32x4 e;
#pragma unroll
            for (int r = 0; r < 4; ++r) {
                e[r] = __expf(acc[sl][m][r] - mx[m][r]);
                sm[m][r] += e[r];
            }
            acc[sl][m] = e;
        }
#pragma unroll
    for (int off = 1; off < 16; off <<= 1)
#pragma unroll
        for (int m = 0; m < 2; ++m)
#pragma unroll
            for (int r = 0; r < 4; ++r)
                sm[m][r] += __shfl_xor(sm[m][r], off, 64);
    if (fr == 0) {
#pragma unroll
        for (int m = 0; m < 2; ++m)
#pragma unroll
            for (int r = 0; r < 4; ++r)
                redbuf[1][g][wg8][m * 16 + il0 + r] = sm[m][r];
    }
    barrier_lgkm();
#pragma unroll
    for (int m = 0; m < 2; ++m)
#pragma unroll
        for (int r = 0; r < 4; ++r) {
            const int row = m * 16 + il0 + r;
            float s = redbuf[1][g][0][row];
#pragma unroll
            for (int q = 1; q < 8; ++q) s += redbuf[1][g][q][row];
            mx[m][r] = 1.f / s;        // reuse mx as inv-sum
        }

    // ---- pack P to fp16 in registers (frees the 64-reg f32 accumulator) ----
    unsigned hp[8][2][2];
#pragma unroll
    for (int sl = 0; sl < 8; ++sl)
#pragma unroll
        for (int m = 0; m < 2; ++m)
#pragma unroll
            for (int rp = 0; rp < 2; ++rp) {
                const unsigned lo = f2h(acc[sl][m][rp * 2 + 0] * mx[m][rp * 2 + 0]);
                const unsigned hi = f2h(acc[sl][m][rp * 2 + 1] * mx[m][rp * 2 + 1]);
                hp[sl][m][rp] = lo | (hi << 16);
            }

    // ---- PV phase ----
    char* pPb = lds + 131072;
    f32x4 apv[2][4] = {};   // [c-frag][i-frag]

#pragma unroll
    for (int jt = 0; jt < 16; ++jt) {
        ushort* pS = (ushort*)(pPb + (jt & 1) * 9216);
        if ((wg8 >> 2) == (jt & 1)) {    // this wave's cols lie in slab jt
            const int colj = (wg8 & 3) * 16 + fr;
#pragma unroll
            for (int m = 0; m < 2; ++m) {
                const int lr = g * 32 + m * 16 + il0;
#pragma unroll
                for (int rp = 0; rp < 2; ++rp) {
                    const unsigned u = hp[jt >> 1][m][rp];
                    pS[(lr + rp * 2 + 0) * 72 + colj] = (ushort)(u & 0xffffu);
                    pS[(lr + rp * 2 + 1) * 72 + colj] = (ushort)(u >> 16);
                }
            }
        }
        asm volatile("s_waitcnt vmcnt(0) lgkmcnt(0)" ::: "memory");
        __builtin_amdgcn_s_barrier();
        __builtin_amdgcn_sched_barrier(0);
        if (jt + 1 < 16) stageV(jt + 1); // overlaps MFMA(jt) + next repack
        const char* vb = lds + (jt & 1) * 65536;
#pragma unroll
        for (int k32 = 0; k32 < 2; ++k32) {
            f16x8 af[2], bf[4];
#pragma unroll
            for (int cf = 0; cf < 2; ++cf) {
                const int row = w * 32 + cf * 16 + fr;
                const int kb2 = (k32 * 64 + ko2) ^ ((fr & 7) << 4);
                af[cf] = *(const f16x8*)(vb + row * 128 + kb2);
            }
#pragma unroll
            for (int f = 0; f < 4; ++f)
                bf[f] = *(const f16x8*)((const char*)pS
                        + (f * 16 + fr) * 144 + k32 * 64 + ko2);
#pragma unroll
            for (int cf = 0; cf < 2; ++cf)
#pragma unroll
                for (int f = 0; f < 4; ++f)
                    apv[cf][f] = __builtin_amdgcn_mfma_f32_16x16x32_f16(
                        af[cf], bf[f], apv[cf][f], 0, 0, 0);
        }
    }

    // ---- gate ----
    float pg[4] = {0.f, 0.f, 0.f, 0.f};
#pragma unroll
    for (int cf = 0; cf < 2; ++cf)
#pragma unroll
        for (int r = 0; r < 4; ++r) {
            const float wv = Wa[w * 32 + cf * 16 + il0 + r];
#pragma unroll
            for (int f = 0; f < 4; ++f)
                pg[f] += wv * apv[cf][f][r];
        }
#pragma unroll
    for (int off = 16; off < 64; off <<= 1)
#pragma unroll
        for (int f = 0; f < 4; ++f)
            pg[f] += __shfl_xor(pg[f], off, 64);
    if (lane < 16) {
#pragma unroll
        for (int f = 0; f < 4; ++f)
            redA[w][f * 16 + fr] = pg[f];
    }
    barrier_lgkm();                      // V reads consumed; redA visible
    if (tid < 64) {
        float s = ba[0];
#pragma unroll
        for (int k = 0; k < 16; ++k) s += redA[k][tid];
        agL[tid] = 1.f / (1.f + __expf(-s));
    }

    // ---- final epilogue: per i-half, fp32 repack (pad 33 dwords) + store ----
    const size_t BCN = (size_t)B * C * N;
    const float gmm = gamma[0];
    float* oS = (float*)lds;             // 512 rows x 33 f32 = 67584 B

#pragma unroll
    for (int h = 0; h < 2; ++h) {
#pragma unroll
        for (int cf = 0; cf < 2; ++cf) {
            const int crow = w * 32 + cf * 16 + il0;
#pragma unroll
            for (int f = 0; f < 2; ++f) {
                const int col = f * 16 + fr;         // 0..31
#pragma unroll
                for (int r = 0; r < 4; ++r)
                    oS[(crow + r) * 33 + col] = apv[cf][2 * h + f][r];
            }
        }
        barrier_lgkm();                  // repack (+ agL at h=0) visible
#pragma unroll
        for (int p = 0; p < 4; ++p) {
            const int ch  = p * 1024 + tid;
            const int row = ch >> 3;     // c
            const int sg  = ch & 7;
            const int ib  = h * 32 + sg * 4;   // i_local base
            f32x4 o = *(const f32x4*)&oS[row * 33 + sg * 4];
            const size_t idx = ((size_t)b * C + row) * N + i0 + ib;
            f32x4 xv = *(const f32x4*)&x[idx];
            f32x4 of, oa;
#pragma unroll
            for (int q = 0; q < 4; ++q) {
                of[q] = gmm * o[q] + xv[q];
                oa[q] = o[q] * (1.f - agL[ib + q]);
            }
            *(f32x4*)&dout[idx]       = of;
            *(f32x4*)&dout[BCN + idx] = oa;
        }
        barrier_lgkm();                  // LDS reads done before next h repack
    }
}

// ---------------------------------------------------------------------------
// Transpose: x[b][c][n] fp32 -> xT[b][n][c] fp16
// ---------------------------------------------------------------------------
__global__ void transpose_x_f16(const float* __restrict__ x,
                                ushort* __restrict__ xT) {
    __shared__ float t[32][33];
    int b  = blockIdx.z;
    int c0 = blockIdx.y * 32;
    int n0 = blockIdx.x * 32;
    int tid = threadIdx.x;
    int tx = tid & 31;
    int ty = tid >> 5;
#pragma unroll
    for (int r = 0; r < 4; ++r)
        t[ty + r * 8][tx] = x[(size_t)b * C * N + (size_t)(c0 + ty + r * 8) * N + n0 + tx];
    __syncthreads();
#pragma unroll
    for (int r = 0; r < 4; ++r) {
        float v = t[tx][ty + r * 8];
        size_t idx = (size_t)b * N * C + (size_t)(n0 + ty + r * 8) * C + c0 + tx;
        xT[idx] = f2h(v);
    }
}

// ---------------------------------------------------------------------------
// Merged weight prep (full fp16): [Wq;Wk] fp16, Wv fp16, bias concat.
// ---------------------------------------------------------------------------
__global__ void prep_weights(const float* __restrict__ Wq, const float* __restrict__ Wk,
                             const float* __restrict__ Wv,
                             const float* __restrict__ bq, const float* __restrict__ bk,
                             ushort* __restrict__ Wqk, ushort* __restrict__ Wv16,
                             float* __restrict__ bqk) {
    int i = blockIdx.x * 256 + threadIdx.x;
    if (i < CQ * C) {
        Wqk[i]          = f2h(Wq[i]);
        Wqk[CQ * C + i] = f2h(Wk[i]);
    }
    if (i < C * C) Wv16[i] = f2h(Wv[i]);
    if (i < 512) bqk[i] = (i < CQ) ? bq[i] : bk[i - CQ];
}

extern "C" void kernel_launch(void* const* d_in, const int* in_sizes, int n_in,
                              void* d_out, int out_size, void* d_ws, size_t ws_size,
                              hipStream_t stream) {
    const float* x     = (const float*)d_in[0];
    const float* Wq    = (const float*)d_in[1];
    const float* bq    = (const float*)d_in[2];
    const float* Wk    = (const float*)d_in[3];
    const float* bk    = (const float*)d_in[4];
    const float* Wv    = (const float*)d_in[5];
    const float* bv    = (const float*)d_in[6];
    const float* Wa    = (const float*)d_in[7];
    const float* ba    = (const float*)d_in[8];
    const float* gamma = (const float*)d_in[9];
    float* out = (float*)d_out;

    // Workspace (MiB offsets)
    const size_t MB = 1048576;
    char* ws = (char*)d_ws;
    ushort* v_     = (ushort*)(ws);                //  0..16  v [b][c][n] fp16
    ushort* qkT    = (ushort*)(ws + 16 * MB);      // 16..32  [b][n][512] fp16
    ushort* Wqk    = (ushort*)(ws + 48 * MB);      // 512 KB  [Wq;Wk] fp16
    ushort* Wv16   = (ushort*)(ws + 48 * MB + 524288);  // 512 KB fp16
    float*  bqk    = (float*)(ws + 49 * MB);       // 2 KB
    ushort* xT     = (ushort*)(ws + 80 * MB);      // 80..96  fp16 [b][n][c]
    const size_t need = 96 * MB;
    if (ws_size < need) return;

    dim3 blk(256);
    transpose_x_f16<<<dim3(N / 32, C / 32, B), blk, 0, stream>>>(x, xT);
    prep_weights<<<dim3(C * C / 256), blk, 0, stream>>>(
        Wq, Wk, Wv, bq, bk, Wqk, Wv16, bqk);

    // qkT[b][n][0..511] = xT[b] . [Wq;Wk]^T + bqk[col]  (fp16 in/out, BK=128)
    gemm128s<3, 2, 1, 1><<<dim3(4, 8, B), blk, 0, stream>>>(
        xT, (long long)N * C, Wqk, 0,
        qkT, (long long)N * 512, bqk, C, 512);
    // v[b][c][n] = Wv . xT[b]^T + bv[row]    (fp16 in/out)
    gemm128s<3, 1, 1, 1><<<dim3(8, 4, B), blk, 0, stream>>>(
        Wv16, 0, xT, (long long)N * C,
        v_, (long long)C * N, bv, C, N);
    // fully fused QK^T + softmax + PV + gate + epilogue -> dout
    fused_attn<<<dim3(16, 16), dim3(1024), 0, stream>>>(
        qkT, v_, Wa, ba, gamma, x, out);
}

// Round 3
// 110.997 us; speedup vs baseline: 1.0010x; 1.0010x over previous
//
#include <hip/hip_runtime.h>
#include <hip/hip_bf16.h>
#include <math.h>

#define B 16
#define C 512
#define CQ 256
#define N 1024

typedef short bf16x8 __attribute__((ext_vector_type(8)));
typedef _Float16 f16x8 __attribute__((ext_vector_type(8)));
typedef float f32x4 __attribute__((ext_vector_type(4)));
typedef unsigned short ushort;

__device__ __forceinline__ unsigned short f2bf(float f) {
    __hip_bfloat16 h = __float2bfloat16(f);
    return *(unsigned short*)&h;
}
__device__ __forceinline__ ushort f2h(float f) {
    _Float16 h = (_Float16)f;
    return *(ushort*)&h;
}
__device__ __forceinline__ float h2f(ushort u) {
    _Float16 h = *(_Float16*)&u;
    return (float)h;
}
__device__ __forceinline__ f16x8 as_h(bf16x8 v) {
    union { bf16x8 s; f16x8 h; } u; u.s = v; return u.h;
}

__device__ __forceinline__ void gload16(void* lds, const void* g) {
    __builtin_amdgcn_global_load_lds(
        (const __attribute__((address_space(1))) void*)g,
        (__attribute__((address_space(3))) void*)lds, 16, 0, 0);
}

__device__ __forceinline__ void barrier_lgkm() {
    asm volatile("s_waitcnt lgkmcnt(0)" ::: "memory");
    __builtin_amdgcn_s_barrier();
    __builtin_amdgcn_sched_barrier(0);
}

// ---------------------------------------------------------------------------
// MFMA GEMM, BK=128, XOR-swizzled LDS. C[b][row][col] = sum_k A[b][row][k] *
// BT[b][col][k] (+bias). 128x128 tile, 256 thr = 4 waves (2x2). K % 128 == 0.
// OUT_MODE: 0 fp32, 1 bf16, 3 fp16. BIAS_MODE: 0 none, 1 row, 2 col.
// XSWZ: XCD remap (grid x*y==32, z==16). DT: 0 bf16 MFMA, 1 fp16 MFMA.
// ---------------------------------------------------------------------------
template<int OUT_MODE, int BIAS_MODE, int XSWZ, int DT>
__global__ __launch_bounds__(256) void gemm128s(
    const ushort* __restrict__ A, long long sA,
    const ushort* __restrict__ BT, long long sB,
    void* __restrict__ Ch, long long sC,
    const float* __restrict__ bias, int K, int Ncols)
{
    __shared__ __align__(16) ushort As[128 * 128];   // 32 KB
    __shared__ __align__(16) ushort Bs[128 * 128];   // 32 KB

    int bx, by, bz;
    if constexpr (XSWZ) {
        const int lin  = blockIdx.x + gridDim.x * (blockIdx.y + gridDim.y * blockIdx.z);
        const int xcd  = lin & 7;
        const int slot = lin >> 3;          // 0..63
        bz = xcd + 8 * (slot >> 5);         // batch
        const int wxy = slot & 31;
        bx = wxy % gridDim.x;
        by = wxy / gridDim.x;
    } else {
        bx = blockIdx.x; by = blockIdx.y; bz = blockIdx.z;
    }

    const int tid  = threadIdx.x;
    const int lane = tid & 63;
    const int w    = tid >> 6;
    const int wr   = (w >> 1) * 64;
    const int wc   = (w & 1) * 64;
    const int fr   = lane & 15;
    const int ko2  = (lane >> 4) * 16;      // byte offset of lane's K-octet

    const int brow = by * 128;
    const int bcol = bx * 128;
    const size_t K2 = (size_t)K * 2;

    const char* Ab = (const char*)(A  + (size_t)bz * sA + (size_t)brow * K);
    const char* Bb = (const char*)(BT + (size_t)bz * sB + (size_t)bcol * K);

    const int sr = tid >> 4;            // staging row base 0..15
    const int ss = (tid & 15) * 16;     // byte seg within 256B row

    f32x4 acc[4][4] = {};

    for (int k0 = 0; k0 < K; k0 += 128) {
#pragma unroll
        for (int p = 0; p < 8; ++p) {
            const int row = p * 16 + sr;
            const size_t so = (size_t)row * K2 + (size_t)k0 * 2
                            + (size_t)(ss ^ ((row & 15) << 4));
            gload16((char*)As + p * 4096 + tid * 16, Ab + so);
            gload16((char*)Bs + p * 4096 + tid * 16, Bb + so);
        }
        __syncthreads();
#pragma unroll
        for (int k32 = 0; k32 < 4; ++k32) {
            const int kswz = (k32 * 64 + ko2) ^ (fr << 4);
            bf16x8 ah[4], bh[4];
#pragma unroll
            for (int m = 0; m < 4; ++m)
                ah[m] = *(const bf16x8*)((const char*)As + (wr + m * 16 + fr) * 256 + kswz);
#pragma unroll
            for (int n = 0; n < 4; ++n)
                bh[n] = *(const bf16x8*)((const char*)Bs + (wc + n * 16 + fr) * 256 + kswz);
            if constexpr (DT == 1) {
#pragma unroll
                for (int m = 0; m < 4; ++m)
#pragma unroll
                    for (int n = 0; n < 4; ++n)
                        acc[m][n] = __builtin_amdgcn_mfma_f32_16x16x32_f16(
                            as_h(ah[m]), as_h(bh[n]), acc[m][n], 0, 0, 0);
            } else {
#pragma unroll
                for (int m = 0; m < 4; ++m)
#pragma unroll
                    for (int n = 0; n < 4; ++n)
                        acc[m][n] = __builtin_amdgcn_mfma_f32_16x16x32_bf16(
                            ah[m], bh[n], acc[m][n], 0, 0, 0);
            }
        }
        __syncthreads();
    }

    // Epilogue: C/D layout col = lane&15, row = (lane>>4)*4 + r
    const int crow = brow + wr + (lane >> 4) * 4;
    const int ccol = bcol + wc + fr;
    const size_t cbase = (size_t)bz * sC;
#pragma unroll
    for (int m = 0; m < 4; ++m) {
#pragma unroll
        for (int n = 0; n < 4; ++n) {
            float cb = (BIAS_MODE == 2) ? bias[ccol + n * 16] : 0.f;
#pragma unroll
            for (int r = 0; r < 4; ++r) {
                int row = crow + m * 16 + r;
                int col = ccol + n * 16;
                float vv = acc[m][n][r];
                if (BIAS_MODE == 1) vv += bias[row];
                if (BIAS_MODE == 2) vv += cb;
                size_t idx = cbase + (size_t)row * Ncols + col;
                if (OUT_MODE == 0)      ((float*)Ch)[idx]  = vv;
                else if (OUT_MODE == 1) ((ushort*)Ch)[idx] = f2bf(vv);
                else                    ((ushort*)Ch)[idx] = f2h(vv);
            }
        }
    }
}

// ---------------------------------------------------------------------------
// Fully fused attention, 1024 threads = 16 waves/CU (4 waves/SIMD; LDS pins
// us to 1 wg/CU).
// amdgpu_waves_per_eu(4,4): closed range => register budget exactly 512/4 =
// 128/wave AND no allocator incentive to spill for unreachable occupancy.
// (launch_bounds(1024,4) in round 2 only set the MIN -> allocator still
// targeted 8 waves/EU, chose 64 VGPRs, spilled ~55 MB/dispatch of scratch:
// FETCH 39->58 MB, WRITE 78->115 MB, counters byte-identical across rounds.)
// Demand by phase: QK ~112 (acc 64 + a_h 32 + addr), pack ~108, PV ~100 —
// all under 128 => spill-free at this cap.
// QK: 16 waves = 2 row-groups x 8 col-waves; acc[8][2]; b_h reused over m.
//     4-buffer depth-2 counted-vmcnt schedule (2 loads/thread => vmcnt 4/2/0).
// PV: 16 waves x 32 channels; V double-buffer + full-drain schedule.
// Epilogue: pad-33 fp32 repack + dual store.
// ---------------------------------------------------------------------------
__global__ __launch_bounds__(1024)
__attribute__((amdgpu_waves_per_eu(4, 4)))
void fused_attn(
    const ushort* __restrict__ qk, const ushort* __restrict__ vmat,
    const float* __restrict__ Wa, const float* __restrict__ ba,
    const float* __restrict__ gamma, const float* __restrict__ x,
    float* __restrict__ dout)
{
    __shared__ __align__(16) char lds[149504];
    __shared__ float redbuf[2][2][8][32];
    __shared__ float redA[16][64];
    __shared__ float agL[64];

    const int tid  = threadIdx.x;
    const int lane = tid & 63;
    const int w    = tid >> 6;           // 0..15
    const int g    = w >> 3;             // QK row group 0/1 (32 rows each)
    const int wg8  = w & 7;              // QK col-wave within group
    const int fr   = lane & 15;
    const int il0  = (lane >> 4) * 4;
    const int ko2  = (lane >> 4) * 16;   // byte offset of lane's K-octet

    // XCD-aware bijective remap (256 wgs, 8 XCDs => 2 batches/XCD)
    const int wgid = blockIdx.x + gridDim.x * blockIdx.y;
    const int nid  = (wgid & 7) * 32 + (wgid >> 3);
    const int b    = nid >> 4;
    const int i0   = (nid & 15) * 64;

    const char* qkB = (const char*)qk + (size_t)b * N * 1024;
    const char* vB  = (const char*)vmat + (size_t)b * C * N * 2;

    const int srow = tid >> 4;          // 0..63
    const int ssg  = (tid & 15) * 16;   // byte seg in 256B row

    // ---- q fragments for K-half 0 only (reloaded for half 1 at s==8) ----
    f16x8 a_h[2][4];
#pragma unroll
    for (int m = 0; m < 2; ++m) {
        const char* qr = qkB + (size_t)(i0 + g * 32 + m * 16 + fr) * 1024
                       + (lane >> 4) * 16;
#pragma unroll
        for (int k32 = 0; k32 < 4; ++k32)
            a_h[m][k32] = *(const f16x8*)(qr + k32 * 64);
    }

    // ---- QK staging: 4 buffers of 32 KB, 2 loads/thread/stage ----
    auto stageK = [&](int s) {
        const int jt_  = s & 7;
        const int ks0_ = s >> 3;
        char* dst = lds + (s & 3) * 32768;
#pragma unroll
        for (int p = 0; p < 2; ++p) {
            const int row = p * 64 + srow;
            const size_t so = (size_t)(jt_ * 128 + row) * 1024 + 512
                            + (size_t)(ks0_ * 256)
                            + (size_t)(ssg ^ ((row & 15) << 4));
            gload16(dst + p * 16384 + tid * 16, qkB + so);
        }
    };

    f32x4 acc[8][2];
#pragma unroll
    for (int sl = 0; sl < 8; ++sl)
#pragma unroll
        for (int m = 0; m < 2; ++m)
            acc[sl][m] = (f32x4){0.f, 0.f, 0.f, 0.f};

    stageK(0);
    stageK(1);

#pragma unroll
    for (int s = 0; s < 16; ++s) {
        if (s == 8) {   // reload q frags for K-half 1 (L2-hot, 8 loads)
#pragma unroll
            for (int m = 0; m < 2; ++m) {
                const char* qr = qkB + (size_t)(i0 + g * 32 + m * 16 + fr) * 1024
                               + 256 + (lane >> 4) * 16;
#pragma unroll
                for (int k32 = 0; k32 < 4; ++k32)
                    a_h[m][k32] = *(const f16x8*)(qr + k32 * 64);
            }
        }
        if (s + 2 < 16) stageK(s + 2);
        if (s < 14)       asm volatile("s_waitcnt vmcnt(4)" ::: "memory");
        else if (s == 14) asm volatile("s_waitcnt vmcnt(2)" ::: "memory");
        else              asm volatile("s_waitcnt vmcnt(0)" ::: "memory");
        __builtin_amdgcn_s_barrier();
        __builtin_amdgcn_sched_barrier(0);
        const char* kb = lds + (s & 3) * 32768;
        const int sl   = s & 7;
        const int jrow = wg8 * 16 + fr;      // 0..127 within slab
        const int rb   = jrow * 256;
#pragma unroll
        for (int k32 = 0; k32 < 4; ++k32) {
            const int kswz = (k32 * 64 + ko2) ^ (fr << 4);
            f16x8 b_h = *(const f16x8*)(kb + rb + kswz);
#pragma unroll
            for (int m = 0; m < 2; ++m)
                acc[sl][m] = __builtin_amdgcn_mfma_f32_16x16x32_f16(
                    a_h[m][k32], b_h, acc[sl][m], 0, 0, 0);
        }
    }

    // ---- V staging (2 x 64 KB), 4 loads/thread ----
    auto stageV = [&](int j) {
        char* dst = lds + (j & 1) * 65536;
#pragma unroll
        for (int p = 0; p < 4; ++p) {
            const int ch = p * 1024 + tid;
            const int row = ch >> 3;
            const int sg  = (ch & 7) * 16;
            const size_t so = (size_t)row * (N * 2) + (size_t)(j * 128)
                            + (size_t)(sg ^ ((row & 7) << 4));
            gload16(dst + ch * 16, vB + so);
        }
    };
    stageV(0);                           // in flight under softmax

    // ---- row max (lgkm-only barriers; vmcnt untouched) ----
    float mx[2][4];
#pragma unroll
    for (int m = 0; m < 2; ++m)
#pragma unroll
        for (int r = 0; r < 4; ++r) {
            float v = acc[0][m][r];
#pragma unroll
            for (int sl = 1; sl < 8; ++sl) v = fmaxf(v, acc[sl][m][r]);
            mx[m][r] = v;
        }
#pragma unroll
    for (int off = 1; off < 16; off <<= 1)
#pragma unroll
        for (int m = 0; m < 2; ++m)
#pragma unroll
            for (int r = 0; r < 4; ++r)
                mx[m][r] = fmaxf(mx[m][r], __shfl_xor(mx[m][r], off, 64));
    if (fr == 0) {
#pragma unroll
        for (int m = 0; m < 2; ++m)
#pragma unroll
            for (int r = 0; r < 4; ++r)
                redbuf[0][g][wg8][m * 16 + il0 + r] = mx[m][r];
    }
    barrier_lgkm();
#pragma unroll
    for (int m = 0; m < 2; ++m)
#pragma unroll
        for (int r = 0; r < 4; ++r) {
            const int row = m * 16 + il0 + r;
            float v = redbuf[0][g][0][row];
#pragma unroll
            for (int q = 1; q < 8; ++q) v = fmaxf(v, redbuf[0][g][q][row]);
            mx[m][r] = v;
        }

    // ---- exp + row sum ----
    float sm[2][4] = {};
#pragma unroll
    for (int sl = 0; sl < 8; ++sl)
#pragma unroll
        for (int m = 0; m < 2; ++m) {
            f32x4 e;
#pragma unroll
            for (int r = 0; r < 4; ++r) {
                e[r] = __expf(acc[sl][m][r] - mx[m][r]);
                sm[m][r] += e[r];
            }
            acc[sl][m] = e;
        }
#pragma unroll
    for (int off = 1; off < 16; off <<= 1)
#pragma unroll
        for (int m = 0; m < 2; ++m)
#pragma unroll
            for (int r = 0; r < 4; ++r)
                sm[m][r] += __shfl_xor(sm[m][r], off, 64);
    if (fr == 0) {
#pragma unroll
        for (int m = 0; m < 2; ++m)
#pragma unroll
            for (int r = 0; r < 4; ++r)
                redbuf[1][g][wg8][m * 16 + il0 + r] = sm[m][r];
    }
    barrier_lgkm();
#pragma unroll
    for (int m = 0; m < 2; ++m)
#pragma unroll
        for (int r = 0; r < 4; ++r) {
            const int row = m * 16 + il0 + r;
            float s = redbuf[1][g][0][row];
#pragma unroll
            for (int q = 1; q < 8; ++q) s += redbuf[1][g][q][row];
            mx[m][r] = 1.f / s;        // reuse mx as inv-sum
        }

    // ---- pack P to fp16 in registers (frees the 64-reg f32 accumulator) ----
    unsigned hp[8][2][2];
#pragma unroll
    for (int sl = 0; sl < 8; ++sl)
#pragma unroll
        for (int m = 0; m < 2; ++m)
#pragma unroll
            for (int rp = 0; rp < 2; ++rp) {
                const unsigned lo = f2h(acc[sl][m][rp * 2 + 0] * mx[m][rp * 2 + 0]);
                const unsigned hi = f2h(acc[sl][m][rp * 2 + 1] * mx[m][rp * 2 + 1]);
                hp[sl][m][rp] = lo | (hi << 16);
            }

    // ---- PV phase ----
    char* pPb = lds + 131072;
    f32x4 apv[2][4] = {};   // [c-frag][i-frag]

#pragma unroll
    for (int jt = 0; jt < 16; ++jt) {
        ushort* pS = (ushort*)(pPb + (jt & 1) * 9216);
        if ((wg8 >> 2) == (jt & 1)) {    // this wave's cols lie in slab jt
            const int colj = (wg8 & 3) * 16 + fr;
#pragma unroll
            for (int m = 0; m < 2; ++m) {
                const int lr = g * 32 + m * 16 + il0;
#pragma unroll
                for (int rp = 0; rp < 2; ++rp) {
                    const unsigned u = hp[jt >> 1][m][rp];
                    pS[(lr + rp * 2 + 0) * 72 + colj] = (ushort)(u & 0xffffu);
                    pS[(lr + rp * 2 + 1) * 72 + colj] = (ushort)(u >> 16);
                }
            }
        }
        asm volatile("s_waitcnt vmcnt(0) lgkmcnt(0)" ::: "memory");
        __builtin_amdgcn_s_barrier();
        __builtin_amdgcn_sched_barrier(0);
        if (jt + 1 < 16) stageV(jt + 1); // overlaps MFMA(jt) + next repack
        const char* vb = lds + (jt & 1) * 65536;
#pragma unroll
        for (int k32 = 0; k32 < 2; ++k32) {
            f16x8 af[2], bf[4];
#pragma unroll
            for (int cf = 0; cf < 2; ++cf) {
                const int row = w * 32 + cf * 16 + fr;
                const int kb2 = (k32 * 64 + ko2) ^ ((fr & 7) << 4);
                af[cf] = *(const f16x8*)(vb + row * 128 + kb2);
            }
#pragma unroll
            for (int f = 0; f < 4; ++f)
                bf[f] = *(const f16x8*)((const char*)pS
                        + (f * 16 + fr) * 144 + k32 * 64 + ko2);
#pragma unroll
            for (int cf = 0; cf < 2; ++cf)
#pragma unroll
                for (int f = 0; f < 4; ++f)
                    apv[cf][f] = __builtin_amdgcn_mfma_f32_16x16x32_f16(
                        af[cf], bf[f], apv[cf][f], 0, 0, 0);
        }
    }

    // ---- gate ----
    float pg[4] = {0.f, 0.f, 0.f, 0.f};
#pragma unroll
    for (int cf = 0; cf < 2; ++cf)
#pragma unroll
        for (int r = 0; r < 4; ++r) {
            const float wv = Wa[w * 32 + cf * 16 + il0 + r];
#pragma unroll
            for (int f = 0; f < 4; ++f)
                pg[f] += wv * apv[cf][f][r];
        }
#pragma unroll
    for (int off = 16; off < 64; off <<= 1)
#pragma unroll
        for (int f = 0; f < 4; ++f)
            pg[f] += __shfl_xor(pg[f], off, 64);
    if (lane < 16) {
#pragma unroll
        for (int f = 0; f < 4; ++f)
            redA[w][f * 16 + fr] = pg[f];
    }
    barrier_lgkm();                      // V reads consumed; redA visible
    if (tid < 64) {
        float s = ba[0];
#pragma unroll
        for (int k = 0; k < 16; ++k) s += redA[k][tid];
        agL[tid] = 1.f / (1.f + __expf(-s));
    }

    // ---- final epilogue: per i-half, fp32 repack (pad 33 dwords) + store ----
    const size_t BCN = (size_t)B * C * N;
    const float gmm = gamma[0];
    float* oS = (float*)lds;             // 512 rows x 33 f32 = 67584 B

#pragma unroll
    for (int h = 0; h < 2; ++h) {
#pragma unroll
        for (int cf = 0; cf < 2; ++cf) {
            const int crow = w * 32 + cf * 16 + il0;
#pragma unroll
            for (int f = 0; f < 2; ++f) {
                const int col = f * 16 + fr;         // 0..31
#pragma unroll
                for (int r = 0; r < 4; ++r)
                    oS[(crow + r) * 33 + col] = apv[cf][2 * h + f][r];
            }
        }
        barrier_lgkm();                  // repack (+ agL at h=0) visible
#pragma unroll
        for (int p = 0; p < 4; ++p) {
            const int ch  = p * 1024 + tid;
            const int row = ch >> 3;     // c
            const int sg  = ch & 7;
            const int ib  = h * 32 + sg * 4;   // i_local base
            f32x4 o = *(const f32x4*)&oS[row * 33 + sg * 4];
            const size_t idx = ((size_t)b * C + row) * N + i0 + ib;
            f32x4 xv = *(const f32x4*)&x[idx];
            f32x4 of, oa;
#pragma unroll
            for (int q = 0; q < 4; ++q) {
                of[q] = gmm * o[q] + xv[q];
                oa[q] = o[q] * (1.f - agL[ib + q]);
            }
            *(f32x4*)&dout[idx]       = of;
            *(f32x4*)&dout[BCN + idx] = oa;
        }
        barrier_lgkm();                  // LDS reads done before next h repack
    }
}

// ---------------------------------------------------------------------------
// Transpose: x[b][c][n] fp32 -> xT[b][n][c] fp16
// ---------------------------------------------------------------------------
__global__ void transpose_x_f16(const float* __restrict__ x,
                                ushort* __restrict__ xT) {
    __shared__ float t[32][33];
    int b  = blockIdx.z;
    int c0 = blockIdx.y * 32;
    int n0 = blockIdx.x * 32;
    int tid = threadIdx.x;
    int tx = tid & 31;
    int ty = tid >> 5;
#pragma unroll
    for (int r = 0; r < 4; ++r)
        t[ty + r * 8][tx] = x[(size_t)b * C * N + (size_t)(c0 + ty + r * 8) * N + n0 + tx];
    __syncthreads();
#pragma unroll
    for (int r = 0; r < 4; ++r) {
        float v = t[tx][ty + r * 8];
        size_t idx = (size_t)b * N * C + (size_t)(n0 + ty + r * 8) * C + c0 + tx;
        xT[idx] = f2h(v);
    }
}

// ---------------------------------------------------------------------------
// Merged weight prep (full fp16): [Wq;Wk] fp16, Wv fp16, bias concat.
// ---------------------------------------------------------------------------
__global__ void prep_weights(const float* __restrict__ Wq, const float* __restrict__ Wk,
                             const float* __restrict__ Wv,
                             const float* __restrict__ bq, const float* __restrict__ bk,
                             ushort* __restrict__ Wqk, ushort* __restrict__ Wv16,
                             float* __restrict__ bqk) {
    int i = blockIdx.x * 256 + threadIdx.x;
    if (i < CQ * C) {
        Wqk[i]          = f2h(Wq[i]);
        Wqk[CQ * C + i] = f2h(Wk[i]);
    }
    if (i < C * C) Wv16[i] = f2h(Wv[i]);
    if (i < 512) bqk[i] = (i < CQ) ? bq[i] : bk[i - CQ];
}

extern "C" void kernel_launch(void* const* d_in, const int* in_sizes, int n_in,
                              void* d_out, int out_size, void* d_ws, size_t ws_size,
                              hipStream_t stream) {
    const float* x     = (const float*)d_in[0];
    const float* Wq    = (const float*)d_in[1];
    const float* bq    = (const float*)d_in[2];
    const float* Wk    = (const float*)d_in[3];
    const float* bk    = (const float*)d_in[4];
    const float* Wv    = (const float*)d_in[5];
    const float* bv    = (const float*)d_in[6];
    const float* Wa    = (const float*)d_in[7];
    const float* ba    = (const float*)d_in[8];
    const float* gamma = (const float*)d_in[9];
    float* out = (float*)d_out;

    // Workspace (MiB offsets)
    const size_t MB = 1048576;
    char* ws = (char*)d_ws;
    ushort* v_     = (ushort*)(ws);                //  0..16  v [b][c][n] fp16
    ushort* qkT    = (ushort*)(ws + 16 * MB);      // 16..32  [b][n][512] fp16
    ushort* Wqk    = (ushort*)(ws + 48 * MB);      // 512 KB  [Wq;Wk] fp16
    ushort* Wv16   = (ushort*)(ws + 48 * MB + 524288);  // 512 KB fp16
    float*  bqk    = (float*)(ws + 49 * MB);       // 2 KB
    ushort* xT     = (ushort*)(ws + 80 * MB);      // 80..96  fp16 [b][n][c]
    const size_t need = 96 * MB;
    if (ws_size < need) return;

    dim3 blk(256);
    transpose_x_f16<<<dim3(N / 32, C / 32, B), blk, 0, stream>>>(x, xT);
    prep_weights<<<dim3(C * C / 256), blk, 0, stream>>>(
        Wq, Wk, Wv, bq, bk, Wqk, Wv16, bqk);

    // qkT[b][n][0..511] = xT[b] . [Wq;Wk]^T + bqk[col]  (fp16 in/out, BK=128)
    gemm128s<3, 2, 1, 1><<<dim3(4, 8, B), blk, 0, stream>>>(
        xT, (long long)N * C, Wqk, 0,
        qkT, (long long)N * 512, bqk, C, 512);
    // v[b][c][n] = Wv . xT[b]^T + bv[row]    (fp16 in/out)
    gemm128s<3, 1, 1, 1><<<dim3(8, 4, B), blk, 0, stream>>>(
        Wv16, 0, xT, (long long)N * C,
        v_, (long long)C * N, bv, C, N);
    // fully fused QK^T + softmax + PV + gate + epilogue -> dout
    fused_attn<<<dim3(16, 16), dim3(1024), 0, stream>>>(
        qkT, v_, Wa, ba, gamma, x, out);
}